// Round 5
// baseline (34.053 us; speedup 1.0000x reference)
//
#include <hip/hip_runtime.h>

// OuterProductMean on MI355X (gfx950).
// out[i,j,p] = b2[p] + sum_{c,d} W2[p, c*32+d] * x[i,d] * x[j,c],  x = seq@W1^T + b1.
// Factored: Y[i][c][p] = sum_d W2[p][c*32+d] * x[i][d]   (4 MB scratch)
//           out[i,j,p] = b2[p] + sum_c x[j,c] * Y[i][c][p]
// k3 budget: HBM write 67MB ~10.6us | LDS crossbar 537MB ~7.8us | VALU ~6.8us.
// Per-thread 8jx8p tile (2.0 FMA per LDS byte) keeps LDS below the HBM floor.

static constexpr int LL  = 512;
static constexpr int IND = 256;
static constexpr int DM  = 32;   // DIM_MSA
static constexpr int PD  = 64;   // PAIR_DIM

// ---------------- k1: x = seq @ W1^T + b1 -> xg [512][32], xTg [32][512]
__global__ __launch_bounds__(256) void k_proj1(const float* __restrict__ seq,
                                               const float* __restrict__ W1,
                                               const float* __restrict__ b1,
                                               float* __restrict__ xg,
                                               float* __restrict__ xTg) {
  __shared__ float part[8][DM];
  const int i   = blockIdx.x;
  const int t   = threadIdx.x;
  const int d   = t & 31;
  const int seg = t >> 5;
  const float* srow = seq + (size_t)i * IND + seg * 32;
  const float* wrow = W1  + (size_t)d * IND + seg * 32;
  float acc = 0.f;
#pragma unroll
  for (int k = 0; k < 32; k += 4) {
    const float4 s4 = *(const float4*)(srow + k);
    const float4 w4 = *(const float4*)(wrow + k);
    acc = fmaf(s4.x, w4.x, acc);
    acc = fmaf(s4.y, w4.y, acc);
    acc = fmaf(s4.z, w4.z, acc);
    acc = fmaf(s4.w, w4.w, acc);
  }
  part[seg][d] = acc;
  __syncthreads();
  if (t < DM) {
    float s = b1[t];
#pragma unroll
    for (int g = 0; g < 8; ++g) s += part[g][t];
    xg[i * DM + t]  = s;
    xTg[t * LL + i] = s;
  }
}

// ---------------- k2: Y[i][c][p] = sum_d W2[p][c*32+d] * x[i][d]
// Grid: 32 c-blocks x 8 i-chunks of 64. All global traffic coalesced via LDS
// staging (rows padded to 36 floats).
__global__ __launch_bounds__(256) void k_y(const float* __restrict__ xg,
                                           const float* __restrict__ W2,
                                           float* __restrict__ Yg) {
  __shared__ __align__(16) float xs[64][36];
  __shared__ __align__(16) float ws2[64][36];
  const int c     = blockIdx.x & 31;
  const int ibase = (blockIdx.x >> 5) * 64;
  const int t     = threadIdx.x;
#pragma unroll
  for (int k = 0; k < 2; ++k) {
    const int idx = t + k * 256;        // 0..511 float4s
    const int il = idx >> 3, d4 = idx & 7;
    const float4 v = *(const float4*)(xg + (size_t)(ibase + il) * DM + d4 * 4);
    *(float4*)&xs[il][d4 * 4] = v;
  }
#pragma unroll
  for (int k = 0; k < 2; ++k) {
    const int idx = t + k * 256;
    const int p = idx >> 3, d4 = idx & 7;
    const float4 v = *(const float4*)(W2 + (size_t)p * (DM * DM) + c * DM + d4 * 4);
    *(float4*)&ws2[p][d4 * 4] = v;
  }
  __syncthreads();
  const int p  = t & 63;
  const int ig = t >> 6;    // 0..3 -> 16 i's each
  float wv[DM];
#pragma unroll
  for (int q = 0; q < 8; ++q) {
    const float4 v = *(const float4*)&ws2[p][q * 4];
    wv[q * 4 + 0] = v.x; wv[q * 4 + 1] = v.y;
    wv[q * 4 + 2] = v.z; wv[q * 4 + 3] = v.w;
  }
#pragma unroll
  for (int il = 0; il < 16; ++il) {
    const int row = ig * 16 + il;
    float a = 0.f;
#pragma unroll
    for (int q = 0; q < 8; ++q) {
      const float4 v = *(const float4*)&xs[row][q * 4];  // broadcast
      a = fmaf(wv[q * 4 + 0], v.x, a);
      a = fmaf(wv[q * 4 + 1], v.y, a);
      a = fmaf(wv[q * 4 + 2], v.z, a);
      a = fmaf(wv[q * 4 + 3], v.w, a);
    }
    Yg[(size_t)(ibase + row) * (DM * PD) + c * PD + p] = a;  // coalesced in p
  }
}

// ---------------- k3: out[i,j,p] = b2[p] + sum_c xT[c][j] * Ys[c][p]
// 128 threads/block, per-thread 8j x 8p (acc=64 VGPR), 4 ds_read_b128 / 64 FMA.
// LDS 24KB -> 6 blocks/CU; grid 2048 oversubscribed for store/compute overlap.
__global__ __launch_bounds__(128, 3) void k_outer(const float* __restrict__ xTg,
                                                  const float* __restrict__ Yg,
                                                  const float* __restrict__ b2,
                                                  float* __restrict__ out) {
  __shared__ __align__(16) float xT[DM * 128];  // [c][j_local] 16 KB
  __shared__ __align__(16) float Ys[DM * PD];   // [c][p]        8 KB
  const int bid = blockIdx.x;
  const int q   = bid & 3;     // j-quarter
  const int i   = bid >> 2;
  const int t   = threadIdx.x;

  // stage xT quarter: [32 c][128 j], coalesced 512B chunks
#pragma unroll
  for (int k = 0; k < 8; ++k) {
    const int idx = t + k * 128;              // float4 index 0..1023
    const int c = idx >> 5, j4 = idx & 31;
    const float4 v = *(const float4*)(xTg + (size_t)c * LL + q * 128 + j4 * 4);
    *(float4*)&xT[c * 128 + j4 * 4] = v;
  }
  // stage Ys (8 KB linear)
  {
    const float4* s = (const float4*)(Yg + (size_t)i * (DM * PD));
#pragma unroll
    for (int k = 0; k < 4; ++k) ((float4*)Ys)[t + k * 128] = s[t + k * 128];
  }

  const int pt = t & 7, jt = t >> 3;   // jt 0..15
  const int j0 = jt * 8;
  const int pA = pt * 4, pB = 32 + pt * 4;
  const float4 bA = *(const float4*)(b2 + pA);
  const float4 bB = *(const float4*)(b2 + pB);

  float acc[8][8];
#pragma unroll
  for (int jj = 0; jj < 8; ++jj) {
    acc[jj][0] = bA.x; acc[jj][1] = bA.y; acc[jj][2] = bA.z; acc[jj][3] = bA.w;
    acc[jj][4] = bB.x; acc[jj][5] = bB.y; acc[jj][6] = bB.z; acc[jj][7] = bB.w;
  }

  __syncthreads();

#pragma unroll 2
  for (int c = 0; c < DM; ++c) {
    const float4 xa = *(const float4*)&xT[c * 128 + j0];
    const float4 xb = *(const float4*)&xT[c * 128 + j0 + 4];
    const float4 ya = *(const float4*)&Ys[c * PD + pA];
    const float4 yb = *(const float4*)&Ys[c * PD + pB];
    const float xv[8] = {xa.x, xa.y, xa.z, xa.w, xb.x, xb.y, xb.z, xb.w};
    const float yv[8] = {ya.x, ya.y, ya.z, ya.w, yb.x, yb.y, yb.z, yb.w};
#pragma unroll
    for (int jj = 0; jj < 8; ++jj)
#pragma unroll
      for (int pp = 0; pp < 8; ++pp)
        acc[jj][pp] = fmaf(xv[jj], yv[pp], acc[jj][pp]);
  }

  float* obase = out + ((size_t)i * LL + q * 128) * PD;
#pragma unroll
  for (int jj = 0; jj < 8; ++jj) {
    float* r = obase + (size_t)(j0 + jj) * PD;
    *(float4*)(r + pA) = make_float4(acc[jj][0], acc[jj][1], acc[jj][2], acc[jj][3]);
    *(float4*)(r + pB) = make_float4(acc[jj][4], acc[jj][5], acc[jj][6], acc[jj][7]);
  }
}

extern "C" void kernel_launch(void* const* d_in, const int* in_sizes, int n_in,
                              void* d_out, int out_size, void* d_ws, size_t ws_size,
                              hipStream_t stream) {
  const float* seq = (const float*)d_in[0];
  const float* W1  = (const float*)d_in[1];
  const float* b1  = (const float*)d_in[2];
  const float* W2  = (const float*)d_in[3];
  const float* b2  = (const float*)d_in[4];
  float* out = (float*)d_out;

  // ws layout (floats): xg[512*32] | xTg[32*512] | Yg[512*32*64]  => ~4.33 MB
  float* xg  = (float*)d_ws;
  float* xTg = xg + LL * DM;
  float* Yg  = xTg + DM * LL;

  k_proj1<<<LL, 256, 0, stream>>>(seq, W1, b1, xg, xTg);
  k_y<<<256, 256, 0, stream>>>(xg, W2, Yg);
  k_outer<<<LL * 4, 128, 0, stream>>>(xTg, Yg, b2, out);
}

// Round 6
// 29.969 us; speedup vs baseline: 1.1363x; 1.1363x over previous
//
#include <hip/hip_runtime.h>

// OuterProductMean on MI355X (gfx950).
// out[i,j,p] = b2[p] + sum_{c,d} W2[p, c*32+d] * x[i,d] * x[j,c],  x = seq@W1^T + b1.
// Factored: Y[i][c][p] = sum_d W2[p][c*32+d] * x[i][d]   (4 MB scratch, f32)
//           out[i,j,p] = b2[p] + sum_c x[j,c] * Y[i][c][p]
// k3 uses v_mfma_f32_32x32x16_f16 (x, Y rounded to fp16; f32 accumulate) so the
// compute leg moves off the VALU -> kernel is a continuously-fed store stream.
// Floor: 67 MB output write ~10.6 us.

static constexpr int LL  = 512;
static constexpr int IND = 256;
static constexpr int DM  = 32;   // DIM_MSA
static constexpr int PD  = 64;   // PAIR_DIM

typedef _Float16 f16x8 __attribute__((ext_vector_type(8)));
typedef float    f32x16 __attribute__((ext_vector_type(16)));

// ---------------- k1: x = seq @ W1^T + b1 -> xg f32 [512][32], xgh f16 [512][32]
__global__ __launch_bounds__(256) void k_proj1(const float* __restrict__ seq,
                                               const float* __restrict__ W1,
                                               const float* __restrict__ b1,
                                               float* __restrict__ xg,
                                               _Float16* __restrict__ xgh) {
  __shared__ float part[8][DM];
  const int i   = blockIdx.x;
  const int t   = threadIdx.x;
  const int d   = t & 31;
  const int seg = t >> 5;
  const float* srow = seq + (size_t)i * IND + seg * 32;
  const float* wrow = W1  + (size_t)d * IND + seg * 32;
  float acc = 0.f;
#pragma unroll
  for (int k = 0; k < 32; k += 4) {
    const float4 s4 = *(const float4*)(srow + k);
    const float4 w4 = *(const float4*)(wrow + k);
    acc = fmaf(s4.x, w4.x, acc);
    acc = fmaf(s4.y, w4.y, acc);
    acc = fmaf(s4.z, w4.z, acc);
    acc = fmaf(s4.w, w4.w, acc);
  }
  part[seg][d] = acc;
  __syncthreads();
  if (t < DM) {
    float s = b1[t];
#pragma unroll
    for (int g = 0; g < 8; ++g) s += part[g][t];
    xg[i * DM + t]  = s;
    xgh[i * DM + t] = (_Float16)s;
  }
}

// ---------------- k2: Y[i][c][p] = sum_d W2[p][c*32+d] * x[i][d]  (f32)
// Grid: 32 c-blocks x 8 i-chunks of 64. All global traffic coalesced via LDS.
__global__ __launch_bounds__(256) void k_y(const float* __restrict__ xg,
                                           const float* __restrict__ W2,
                                           float* __restrict__ Yg) {
  __shared__ __align__(16) float xs[64][36];
  __shared__ __align__(16) float ws2[64][36];
  const int c     = blockIdx.x & 31;
  const int ibase = (blockIdx.x >> 5) * 64;
  const int t     = threadIdx.x;
#pragma unroll
  for (int k = 0; k < 2; ++k) {
    const int idx = t + k * 256;
    const int il = idx >> 3, d4 = idx & 7;
    const float4 v = *(const float4*)(xg + (size_t)(ibase + il) * DM + d4 * 4);
    *(float4*)&xs[il][d4 * 4] = v;
  }
#pragma unroll
  for (int k = 0; k < 2; ++k) {
    const int idx = t + k * 256;
    const int p = idx >> 3, d4 = idx & 7;
    const float4 v = *(const float4*)(W2 + (size_t)p * (DM * DM) + c * DM + d4 * 4);
    *(float4*)&ws2[p][d4 * 4] = v;
  }
  __syncthreads();
  const int p  = t & 63;
  const int ig = t >> 6;
  float wv[DM];
#pragma unroll
  for (int q = 0; q < 8; ++q) {
    const float4 v = *(const float4*)&ws2[p][q * 4];
    wv[q * 4 + 0] = v.x; wv[q * 4 + 1] = v.y;
    wv[q * 4 + 2] = v.z; wv[q * 4 + 3] = v.w;
  }
#pragma unroll
  for (int il = 0; il < 16; ++il) {
    const int row = ig * 16 + il;
    float a = 0.f;
#pragma unroll
    for (int q = 0; q < 8; ++q) {
      const float4 v = *(const float4*)&xs[row][q * 4];
      a = fmaf(wv[q * 4 + 0], v.x, a);
      a = fmaf(wv[q * 4 + 1], v.y, a);
      a = fmaf(wv[q * 4 + 2], v.z, a);
      a = fmaf(wv[q * 4 + 3], v.w, a);
    }
    Yg[(size_t)(ibase + row) * (DM * PD) + c * PD + p] = a;
  }
}

// ---------------- k3: MFMA. Block = 128 thr (2 waves), tile: 1 i x 128 j x 64 p.
// Wave w owns p-half w. 4 j-subtiles of 32 -> 8 x mfma_f32_32x32x16_f16 per wave.
// A[m=j][k=c] = x_f16[j][c]; B[k=c][n=p] = Y_f16[p][c] (transposed at staging).
// Frag layout (CDNA): m/n = lane&31, k = 8*(lane>>5)+elem.
// D: col(p) = lane&31, row(j) = (reg&3) + 8*(reg>>2) + 4*(lane>>5).
static constexpr int XPAD = 40;  // f16 row stride: 80B, keeps b128 16B-aligned

__global__ __launch_bounds__(128, 4) void k_outer(const _Float16* __restrict__ xgh,
                                                  const float* __restrict__ Yg,
                                                  const float* __restrict__ b2,
                                                  float* __restrict__ out) {
  __shared__ __align__(16) _Float16 xbs[128 * XPAD];  // 10 KB: [j_local][c]
  __shared__ __align__(16) _Float16 ybs[PD * XPAD];   //  5 KB: [p][c]
  const int bid = blockIdx.x;
  const int q   = bid & 3;     // j-quarter
  const int i   = bid >> 2;
  const int t   = threadIdx.x;

  // stage x rows (fp16, row j = t), 64B per row
  {
    const f16x8* src = (const f16x8*)(xgh + (size_t)(q * 128 + t) * DM);
    _Float16* dst = &xbs[t * XPAD];
    *(f16x8*)(dst)      = src[0];
    *(f16x8*)(dst + 8)  = src[1];
    *(f16x8*)(dst + 16) = src[2];
    *(f16x8*)(dst + 24) = src[3];
  }
  // stage Y[i]: read f32 [c][p] coalesced, write f16 transposed [p][c]
  {
    const float4* src = (const float4*)(Yg + (size_t)i * (DM * PD));
#pragma unroll
    for (int k = 0; k < 4; ++k) {
      const int q4 = t + k * 128;          // 0..511
      const int c = q4 >> 4, p0 = (q4 & 15) * 4;
      const float4 v = src[q4];
      ybs[(p0 + 0) * XPAD + c] = (_Float16)v.x;
      ybs[(p0 + 1) * XPAD + c] = (_Float16)v.y;
      ybs[(p0 + 2) * XPAD + c] = (_Float16)v.z;
      ybs[(p0 + 3) * XPAD + c] = (_Float16)v.w;
    }
  }
  __syncthreads();

  const int lane = t & 63;
  const int w    = t >> 6;        // p-half (0/1)
  const int l31  = lane & 31;
  const int lh   = lane >> 5;

  // B frags: fixed per wave. k-halves 0-15 / 16-31.
  const int bi = (w * 32 + l31) * XPAD + lh * 8;
  const f16x8 b0 = *(const f16x8*)&ybs[bi];
  const f16x8 b1 = *(const f16x8*)&ybs[bi + 16];
  const float bias = b2[w * 32 + l31];

  float* obase = out + (((size_t)i * LL + q * 128) * PD) + w * 32 + l31;

#pragma unroll
  for (int jt = 0; jt < 4; ++jt) {
    const int ai = (jt * 32 + l31) * XPAD + lh * 8;
    const f16x8 a0 = *(const f16x8*)&xbs[ai];
    const f16x8 a1 = *(const f16x8*)&xbs[ai + 16];
    f32x16 acc = {};
    acc = __builtin_amdgcn_mfma_f32_32x32x16_f16(a0, b0, acc, 0, 0, 0);
    acc = __builtin_amdgcn_mfma_f32_32x32x16_f16(a1, b1, acc, 0, 0, 0);
#pragma unroll
    for (int r = 0; r < 16; ++r) {
      const int row = (r & 3) + 8 * (r >> 2) + 4 * lh;   // j within subtile
      obase[(size_t)(jt * 32 + row) * PD] = acc[r] + bias;
    }
  }
}

extern "C" void kernel_launch(void* const* d_in, const int* in_sizes, int n_in,
                              void* d_out, int out_size, void* d_ws, size_t ws_size,
                              hipStream_t stream) {
  const float* seq = (const float*)d_in[0];
  const float* W1  = (const float*)d_in[1];
  const float* b1  = (const float*)d_in[2];
  const float* W2  = (const float*)d_in[3];
  const float* b2  = (const float*)d_in[4];
  float* out = (float*)d_out;

  // ws layout: xg f32[16K] | xgh f16[16K] (8K floats) | Yg f32[1M]  => ~4.3 MB
  float* xg  = (float*)d_ws;
  _Float16* xgh = (_Float16*)(xg + LL * DM);
  float* Yg  = (float*)(xg + LL * DM + LL * DM / 2);

  k_proj1<<<LL, 256, 0, stream>>>(seq, W1, b1, xg, xgh);
  k_y<<<256, 256, 0, stream>>>(xg, W2, Yg);
  k_outer<<<LL * 4, 128, 0, stream>>>(xgh, Yg, b2, out);
}

// Round 7
// 28.545 us; speedup vs baseline: 1.1930x; 1.0499x over previous
//
#include <hip/hip_runtime.h>

// OuterProductMean on MI355X (gfx950).
// out[i,j,p] = b2[p] + sum_{c,d} W2[p, c*32+d] * x[i,d] * x[j,c],  x = seq@W1^T + b1.
// Factored: Y[i][c][p] = sum_d W2[p][c*32+d] * x[i][d]  (f16, 2 MB scratch)
//           out[i,j,p] = b2[p] + sum_c x[j,c] * Y[i][c][p]
// k3: v_mfma_f32_32x32x16_f16 + LDS-transpose epilogue so all HBM stores are
// dense global_store_dwordx4 (the measured-6.3TB/s pattern). Floor ~10.6 us.

static constexpr int LL  = 512;
static constexpr int IND = 256;
static constexpr int DM  = 32;   // DIM_MSA
static constexpr int PD  = 64;   // PAIR_DIM

typedef _Float16 f16x8 __attribute__((ext_vector_type(8)));
typedef float    f32x16 __attribute__((ext_vector_type(16)));

// ---------------- k1: x = seq @ W1^T + b1 -> xg f32 [512][32], xgh f16 [512][32]
__global__ __launch_bounds__(256) void k_proj1(const float* __restrict__ seq,
                                               const float* __restrict__ W1,
                                               const float* __restrict__ b1,
                                               float* __restrict__ xg,
                                               _Float16* __restrict__ xgh) {
  __shared__ float part[8][DM];
  const int i   = blockIdx.x;
  const int t   = threadIdx.x;
  const int d   = t & 31;
  const int seg = t >> 5;
  const float* srow = seq + (size_t)i * IND + seg * 32;
  const float* wrow = W1  + (size_t)d * IND + seg * 32;
  float acc = 0.f;
#pragma unroll
  for (int k = 0; k < 32; k += 4) {
    const float4 s4 = *(const float4*)(srow + k);
    const float4 w4 = *(const float4*)(wrow + k);
    acc = fmaf(s4.x, w4.x, acc);
    acc = fmaf(s4.y, w4.y, acc);
    acc = fmaf(s4.z, w4.z, acc);
    acc = fmaf(s4.w, w4.w, acc);
  }
  part[seg][d] = acc;
  __syncthreads();
  if (t < DM) {
    float s = b1[t];
#pragma unroll
    for (int g = 0; g < 8; ++g) s += part[g][t];
    xg[i * DM + t]  = s;
    xgh[i * DM + t] = (_Float16)s;
  }
}

// ---------------- k2: Ygh[i][c][p] = (f16) sum_d W2[p][c*32+d] * x[i][d]
// Grid: 32 c-blocks x 8 i-chunks of 64. Coalesced reads via LDS staging;
// output stores are contiguous 128B u16 wave-stores (p fastest).
__global__ __launch_bounds__(256) void k_y(const float* __restrict__ xg,
                                           const float* __restrict__ W2,
                                           _Float16* __restrict__ Ygh) {
  __shared__ __align__(16) float xs[64][36];
  __shared__ __align__(16) float ws2[64][36];
  const int c     = blockIdx.x & 31;
  const int ibase = (blockIdx.x >> 5) * 64;
  const int t     = threadIdx.x;
#pragma unroll
  for (int k = 0; k < 2; ++k) {
    const int idx = t + k * 256;
    const int il = idx >> 3, d4 = idx & 7;
    const float4 v = *(const float4*)(xg + (size_t)(ibase + il) * DM + d4 * 4);
    *(float4*)&xs[il][d4 * 4] = v;
  }
#pragma unroll
  for (int k = 0; k < 2; ++k) {
    const int idx = t + k * 256;
    const int p = idx >> 3, d4 = idx & 7;
    const float4 v = *(const float4*)(W2 + (size_t)p * (DM * DM) + c * DM + d4 * 4);
    *(float4*)&ws2[p][d4 * 4] = v;
  }
  __syncthreads();
  const int p  = t & 63;
  const int ig = t >> 6;
  float wv[DM];
#pragma unroll
  for (int q = 0; q < 8; ++q) {
    const float4 v = *(const float4*)&ws2[p][q * 4];
    wv[q * 4 + 0] = v.x; wv[q * 4 + 1] = v.y;
    wv[q * 4 + 2] = v.z; wv[q * 4 + 3] = v.w;
  }
#pragma unroll
  for (int il = 0; il < 16; ++il) {
    const int row = ig * 16 + il;
    float a = 0.f;
#pragma unroll
    for (int q = 0; q < 8; ++q) {
      const float4 v = *(const float4*)&xs[row][q * 4];
      a = fmaf(wv[q * 4 + 0], v.x, a);
      a = fmaf(wv[q * 4 + 1], v.y, a);
      a = fmaf(wv[q * 4 + 2], v.z, a);
      a = fmaf(wv[q * 4 + 3], v.w, a);
    }
    Ygh[((size_t)(ibase + row) * DM + c) * PD + p] = (_Float16)a;
  }
}

// ---------------- k3: MFMA + LDS-transpose epilogue.
// Block = 128 thr (2 waves), tile: 1 i x 128 j x 64 p; wave w owns p-half w.
// A[m=j][k=c] from xbs rows; B[k=c][n=p] frags gathered once from ybs [c][p].
// D layout: col(p)=lane&31, row(j)=(reg&3)+8*(reg>>2)+4*(lane>>5)  [verified R6].
// Epilogue per 32-j subtile: acc -> obuf[32][64] -> dense dwordx4 stores.
static constexpr int XPAD = 40;  // f16 row stride 80B (16B-aligned b128 reads)

__global__ __launch_bounds__(128, 4) void k_outer(const _Float16* __restrict__ xgh,
                                                  const _Float16* __restrict__ Ygh,
                                                  const float* __restrict__ b2,
                                                  float* __restrict__ out) {
  __shared__ __align__(16) _Float16 xbs[128 * XPAD];  // 10 KB: [j_local][c]
  __shared__ __align__(16) _Float16 ybs[DM * PD];     //  4 KB: [c][p] linear
  __shared__ __align__(16) float    obuf[32 * PD];    //  8 KB epilogue staging
  const int q = blockIdx.x & 3;     // j-quarter
  const int i = blockIdx.x >> 2;
  const int t = threadIdx.x;

  // stage x rows (row j = t): 64B per thread, coalesced
  {
    const f16x8* src = (const f16x8*)(xgh + (size_t)(q * 128 + t) * DM);
    _Float16* dst = &xbs[t * XPAD];
    *(f16x8*)(dst)      = src[0];
    *(f16x8*)(dst + 8)  = src[1];
    *(f16x8*)(dst + 16) = src[2];
    *(f16x8*)(dst + 24) = src[3];
  }
  // stage Ygh[i] (4KB) linear
  {
    const f16x8* ys = (const f16x8*)(Ygh + (size_t)i * (DM * PD));
    *(f16x8*)&ybs[t * 8]        = ys[t];
    *(f16x8*)&ybs[1024 + t * 8] = ys[128 + t];
  }
  __syncthreads();

  const int lane = t & 63;
  const int w    = t >> 6;        // p-half (0/1)
  const int l31  = lane & 31;
  const int lh   = lane >> 5;
  const int pn   = w * 32 + l31;  // this lane's p (n index)

  // B frags: one-time scattered u16 gather (2-way bank alias = free)
  f16x8 b0, b1;
#pragma unroll
  for (int e = 0; e < 8; ++e) {
    b0[e] = ybs[(lh * 8 + e) * PD + pn];
    b1[e] = ybs[(16 + lh * 8 + e) * PD + pn];
  }
  // bias for epilogue: (t + k*128)&15 == t&15 for all k -> one float4
  const float4 bias4 = *(const float4*)(b2 + (t & 15) * 4);

  const size_t orow0 = ((size_t)i * LL + q * 128) * PD;

#pragma unroll
  for (int jt = 0; jt < 4; ++jt) {
    const int ai = (jt * 32 + l31) * XPAD + lh * 8;
    const f16x8 a0 = *(const f16x8*)&xbs[ai];
    const f16x8 a1 = *(const f16x8*)&xbs[ai + 16];
    f32x16 acc = {};
    acc = __builtin_amdgcn_mfma_f32_32x32x16_f16(a0, b0, acc, 0, 0, 0);
    acc = __builtin_amdgcn_mfma_f32_32x32x16_f16(a1, b1, acc, 0, 0, 0);
    // scatter acc into obuf (banks: lane&31 -> 2-way max)
#pragma unroll
    for (int r = 0; r < 16; ++r) {
      const int row = (r & 3) + 8 * (r >> 2) + 4 * lh;  // j within subtile
      obuf[row * PD + pn] = acc[r];
    }
    __syncthreads();
    // dense epilogue: 4 x (b128 read + bias + dwordx4 store) per thread
#pragma unroll
    for (int k = 0; k < 4; ++k) {
      const int idx = t + k * 128;           // float4 index 0..511
      float4 v = *(const float4*)&obuf[idx * 4];
      v.x += bias4.x; v.y += bias4.y; v.z += bias4.z; v.w += bias4.w;
      *(float4*)(out + orow0 + (size_t)(jt * 32) * PD + idx * 4) = v;
    }
    __syncthreads();
  }
}

extern "C" void kernel_launch(void* const* d_in, const int* in_sizes, int n_in,
                              void* d_out, int out_size, void* d_ws, size_t ws_size,
                              hipStream_t stream) {
  const float* seq = (const float*)d_in[0];
  const float* W1  = (const float*)d_in[1];
  const float* b1  = (const float*)d_in[2];
  const float* W2  = (const float*)d_in[3];
  const float* b2  = (const float*)d_in[4];
  float* out = (float*)d_out;

  // ws layout: xg f32[512*32] | xgh f16[512*32] | Ygh f16[512*32*64]  => ~2.2 MB
  float* xg     = (float*)d_ws;
  _Float16* xgh = (_Float16*)(xg + LL * DM);
  _Float16* Ygh = (_Float16*)(xg + LL * DM + LL * DM / 2);

  k_proj1<<<LL, 256, 0, stream>>>(seq, W1, b1, xg, xgh);
  k_y<<<256, 256, 0, stream>>>(xg, W2, Ygh);
  k_outer<<<LL * 4, 128, 0, stream>>>(xgh, Ygh, b2, out);
}

// Round 8
// 27.541 us; speedup vs baseline: 1.2365x; 1.0365x over previous
//
#include <hip/hip_runtime.h>

// OuterProductMean on MI355X (gfx950).
// out[i,j,p] = b2[p] + sum_{c,d} W2[p, c*32+d] * x[i,d] * x[j,c],  x = seq@W1^T + b1.
// Factored: Y[i][c][p] = sum_d W2[p][c*32+d] * x[i][d]  (f16, 2 MB scratch)
//           out[i,j,p] = b2[p] + sum_c x[j,c] * Y[i][c][p]
// k3: v_mfma_f32_32x32x16_f16 + LDS-transpose epilogue (dense dwordx4 stores).
// Barriers are LGKM-ONLY (raw s_barrier) so global stores stay in flight across
// them -- __syncthreads would drain vmcnt(0) and serialize compute vs stores.
// 2 i-tiles per block with double-buffered Y (issue-early/write-late prefetch).
// Floor: 67 MB output write ~10.6 us.

static constexpr int LL  = 512;
static constexpr int IND = 256;
static constexpr int DM  = 32;   // DIM_MSA
static constexpr int PD  = 64;   // PAIR_DIM

typedef _Float16 f16x8 __attribute__((ext_vector_type(8)));
typedef float    f32x16 __attribute__((ext_vector_type(16)));

// LDS-only barrier: order ds ops across waves WITHOUT draining global stores.
#define LGKM_BARRIER() do { \
    asm volatile("s_waitcnt lgkmcnt(0)" ::: "memory"); \
    __builtin_amdgcn_s_barrier(); \
  } while (0)

// ---------------- k1: x = seq @ W1^T + b1 -> xg f32 [512][32], xgh f16 [512][32]
__global__ __launch_bounds__(256) void k_proj1(const float* __restrict__ seq,
                                               const float* __restrict__ W1,
                                               const float* __restrict__ b1,
                                               float* __restrict__ xg,
                                               _Float16* __restrict__ xgh) {
  __shared__ float part[8][DM];
  const int i   = blockIdx.x;
  const int t   = threadIdx.x;
  const int d   = t & 31;
  const int seg = t >> 5;
  const float* srow = seq + (size_t)i * IND + seg * 32;
  const float* wrow = W1  + (size_t)d * IND + seg * 32;
  float acc = 0.f;
#pragma unroll
  for (int k = 0; k < 32; k += 4) {
    const float4 s4 = *(const float4*)(srow + k);
    const float4 w4 = *(const float4*)(wrow + k);
    acc = fmaf(s4.x, w4.x, acc);
    acc = fmaf(s4.y, w4.y, acc);
    acc = fmaf(s4.z, w4.z, acc);
    acc = fmaf(s4.w, w4.w, acc);
  }
  part[seg][d] = acc;
  __syncthreads();
  if (t < DM) {
    float s = b1[t];
#pragma unroll
    for (int g = 0; g < 8; ++g) s += part[g][t];
    xg[i * DM + t]  = s;
    xgh[i * DM + t] = (_Float16)s;
  }
}

// ---------------- k2: Ygh[i][c][p] = (f16) sum_d W2[p][c*32+d] * x[i][d]
__global__ __launch_bounds__(256) void k_y(const float* __restrict__ xg,
                                           const float* __restrict__ W2,
                                           _Float16* __restrict__ Ygh) {
  __shared__ __align__(16) float xs[64][36];
  __shared__ __align__(16) float ws2[64][36];
  const int c     = blockIdx.x & 31;
  const int ibase = (blockIdx.x >> 5) * 64;
  const int t     = threadIdx.x;
#pragma unroll
  for (int k = 0; k < 2; ++k) {
    const int idx = t + k * 256;
    const int il = idx >> 3, d4 = idx & 7;
    const float4 v = *(const float4*)(xg + (size_t)(ibase + il) * DM + d4 * 4);
    *(float4*)&xs[il][d4 * 4] = v;
  }
#pragma unroll
  for (int k = 0; k < 2; ++k) {
    const int idx = t + k * 256;
    const int p = idx >> 3, d4 = idx & 7;
    const float4 v = *(const float4*)(W2 + (size_t)p * (DM * DM) + c * DM + d4 * 4);
    *(float4*)&ws2[p][d4 * 4] = v;
  }
  __syncthreads();
  const int p  = t & 63;
  const int ig = t >> 6;
  float wv[DM];
#pragma unroll
  for (int q = 0; q < 8; ++q) {
    const float4 v = *(const float4*)&ws2[p][q * 4];
    wv[q * 4 + 0] = v.x; wv[q * 4 + 1] = v.y;
    wv[q * 4 + 2] = v.z; wv[q * 4 + 3] = v.w;
  }
#pragma unroll
  for (int il = 0; il < 16; ++il) {
    const int row = ig * 16 + il;
    float a = 0.f;
#pragma unroll
    for (int q = 0; q < 8; ++q) {
      const float4 v = *(const float4*)&xs[row][q * 4];
      a = fmaf(wv[q * 4 + 0], v.x, a);
      a = fmaf(wv[q * 4 + 1], v.y, a);
      a = fmaf(wv[q * 4 + 2], v.z, a);
      a = fmaf(wv[q * 4 + 3], v.w, a);
    }
    Ygh[((size_t)(ibase + row) * DM + c) * PD + p] = (_Float16)a;
  }
}

// ---------------- k3: MFMA + LDS-transpose epilogue, 2 i-tiles per block.
// Block = 128 thr (2 waves), tile: 1 i x 128 j x 64 p; wave w owns p-half w.
// D layout: col(p)=lane&31, row(j)=(reg&3)+8*(reg>>2)+4*(lane>>5)  [verified R6].
static constexpr int XPAD = 40;  // f16 row stride 80B (16B-aligned b128 reads)

__global__ __launch_bounds__(128, 3) void k_outer(const _Float16* __restrict__ xgh,
                                                  const _Float16* __restrict__ Ygh,
                                                  const float* __restrict__ b2,
                                                  float* __restrict__ out) {
  __shared__ __align__(16) _Float16 xbs[128 * XPAD];  // 10 KB: [j_local][c]
  __shared__ __align__(16) _Float16 ybs[2 * DM * PD]; // 2 x 4 KB: [c][p]
  __shared__ __align__(16) float    obuf[32 * PD];    // 8 KB epilogue staging
  const int q  = blockIdx.x & 3;       // j-quarter
  const int i0 = blockIdx.x >> 2;      // first i; second is i0+256
  const int t  = threadIdx.x;

  const int lane = t & 63;
  const int w    = t >> 6;        // p-half (0/1)
  const int l31  = lane & 31;
  const int lh   = lane >> 5;
  const int pn   = w * 32 + l31;  // this lane's p (n index)
  const float4 bias4 = *(const float4*)(b2 + (t & 15) * 4);

  // stage x rows (row j = t): 64B per thread, coalesced; q-dependent only
  {
    const f16x8* src = (const f16x8*)(xgh + (size_t)(q * 128 + t) * DM);
    _Float16* dst = &xbs[t * XPAD];
    *(f16x8*)(dst)      = src[0];
    *(f16x8*)(dst + 8)  = src[1];
    *(f16x8*)(dst + 16) = src[2];
    *(f16x8*)(dst + 24) = src[3];
  }
  // stage Ygh[i0] into ybs[0]
  {
    const f16x8* ys = (const f16x8*)(Ygh + (size_t)i0 * (DM * PD));
    const f16x8 a = ys[t];
    const f16x8 b = ys[128 + t];
    *(f16x8*)&ybs[t * 8]        = a;
    *(f16x8*)&ybs[1024 + t * 8] = b;
  }
  LGKM_BARRIER();

  // issue-early: Ygh[i1] global loads in flight across tile-0 compute
  const f16x8* ys1 = (const f16x8*)(Ygh + (size_t)(i0 + 256) * (DM * PD));
  const f16x8 n0 = ys1[t];
  const f16x8 n1 = ys1[128 + t];

  auto process = [&](int i, const _Float16* __restrict__ yb) {
    // B frags: one-time scattered u16 gather (2-way bank alias = free)
    f16x8 b0, b1;
#pragma unroll
    for (int e = 0; e < 8; ++e) {
      b0[e] = yb[(lh * 8 + e) * PD + pn];
      b1[e] = yb[(16 + lh * 8 + e) * PD + pn];
    }
    const size_t orow0 = ((size_t)i * LL + q * 128) * PD;
#pragma unroll
    for (int jt = 0; jt < 4; ++jt) {
      const int ai = (jt * 32 + l31) * XPAD + lh * 8;
      const f16x8 a0 = *(const f16x8*)&xbs[ai];
      const f16x8 a1 = *(const f16x8*)&xbs[ai + 16];
      f32x16 acc = {};
      acc = __builtin_amdgcn_mfma_f32_32x32x16_f16(a0, b0, acc, 0, 0, 0);
      acc = __builtin_amdgcn_mfma_f32_32x32x16_f16(a1, b1, acc, 0, 0, 0);
      // scatter acc into obuf (2-way bank alias max = free)
#pragma unroll
      for (int r = 0; r < 16; ++r) {
        const int row = (r & 3) + 8 * (r >> 2) + 4 * lh;  // j within subtile
        obuf[row * PD + pn] = acc[r];
      }
      LGKM_BARRIER();
      // dense epilogue: 4 x (b128 read + bias + dwordx4 store) per thread;
      // stores stay in flight past the next barrier (lgkm-only).
#pragma unroll
      for (int k = 0; k < 4; ++k) {
        const int idx = t + k * 128;           // float4 index 0..511
        float4 v = *(const float4*)&obuf[idx * 4];
        v.x += bias4.x; v.y += bias4.y; v.z += bias4.z; v.w += bias4.w;
        *(float4*)(out + orow0 + (size_t)(jt * 32) * PD + idx * 4) = v;
      }
      LGKM_BARRIER();
    }
  };

  process(i0, ybs);

  // write-late: commit prefetched Y[i1] (vmcnt satisfied by register dep)
  *(f16x8*)&ybs[2048 + t * 8]        = n0;
  *(f16x8*)&ybs[2048 + 1024 + t * 8] = n1;
  LGKM_BARRIER();

  process(i0 + 256, ybs + 2048);
}

extern "C" void kernel_launch(void* const* d_in, const int* in_sizes, int n_in,
                              void* d_out, int out_size, void* d_ws, size_t ws_size,
                              hipStream_t stream) {
  const float* seq = (const float*)d_in[0];
  const float* W1  = (const float*)d_in[1];
  const float* b1  = (const float*)d_in[2];
  const float* W2  = (const float*)d_in[3];
  const float* b2  = (const float*)d_in[4];
  float* out = (float*)d_out;

  // ws layout: xg f32[512*32] | xgh f16[512*32] | Ygh f16[512*32*64]  => ~2.2 MB
  float* xg     = (float*)d_ws;
  _Float16* xgh = (_Float16*)(xg + LL * DM);
  _Float16* Ygh = (_Float16*)(xg + LL * DM + LL * DM / 2);

  k_proj1<<<LL, 256, 0, stream>>>(seq, W1, b1, xg, xgh);
  k_y<<<256, 256, 0, stream>>>(xg, W2, Ygh);
  k_outer<<<LL * 2, 128, 0, stream>>>(xgh, Ygh, b2, out);
}